// Round 1
// baseline (118.726 us; speedup 1.0000x reference)
//
#include <hip/hip_runtime.h>

// CategorySpecificMLP: out = relu(x @ W1[cat] + b1[cat]) @ W2[cat] + b2[cat]
// N=8192 tokens, C=100 categories, D=128, H=128, O=64, fp32.
//
// Strategy: bucket tokens by category (4 tiny prologue kernels), then one
// workgroup per (category, 64-token chunk) does both layers with LDS-staged
// x and W1 tiles. Weight traffic drops from ~786MB (per-token gather) to
// ~20MB (per-chunk reuse).

#define N_TOK 8192
#define C_CAT 100
#define D_IN  128
#define H_MID 128
#define O_OUT 64
#define TPB   64                          // tokens per mlp block
#define MAX_ITEMS (C_CAT + N_TOK / TPB)   // 228: sum ceil(n_c/TPB) <= C + N/TPB

// ws layout (ints):
//   [0,128)            per-category counts (zeroed each call)
//   [128,256)          cursors (set by scan, consumed by scatter)
//   [256]              n_items
//   [272, 272+3*228)   work items (cat, start, cnt)
//   [1024, 1024+N)     token ids sorted by category

__global__ void zero_counts_kernel(int* __restrict__ ws) {
  int t = threadIdx.x;
  if (t < 128) ws[t] = 0;
}

__global__ void count_kernel(const int* __restrict__ cat_ids, int* __restrict__ ws) {
  int n = blockIdx.x * blockDim.x + threadIdx.x;
  atomicAdd(&ws[cat_ids[n]], 1);
}

__global__ void scan_build_kernel(int* __restrict__ ws) {
  // single block, 128 threads: prefix-scan counts and chunk counts, build work items
  __shared__ int sc[128], sk[128];
  int t = threadIdx.x;
  int v  = (t < C_CAT) ? ws[t] : 0;
  int ck = (v + TPB - 1) / TPB;
  sc[t] = v; sk[t] = ck;
  __syncthreads();
  for (int off = 1; off < 128; off <<= 1) {
    int a = (t >= off) ? sc[t - off] : 0;
    int b = (t >= off) ? sk[t - off] : 0;
    __syncthreads();
    sc[t] += a; sk[t] += b;
    __syncthreads();
  }
  if (t < C_CAT) {
    int start = sc[t] - v;     // exclusive prefix of counts
    int ibase = sk[t] - ck;    // exclusive prefix of chunk counts
    ws[128 + t] = start;       // scatter cursor
    int* items = ws + 272;
    for (int k = 0; k < ck; ++k) {
      items[3 * (ibase + k) + 0] = t;
      items[3 * (ibase + k) + 1] = start + k * TPB;
      items[3 * (ibase + k) + 2] = min(TPB, v - k * TPB);
    }
  }
  if (t == 127) ws[256] = sk[127];
}

__global__ void scatter_kernel(const int* __restrict__ cat_ids, int* __restrict__ ws) {
  int n = blockIdx.x * blockDim.x + threadIdx.x;
  int c = cat_ids[n];
  int pos = atomicAdd(&ws[128 + c], 1);
  ws[1024 + pos] = n;
}

__global__ __launch_bounds__(256) void mlp_kernel(
    const float* __restrict__ x,  const float* __restrict__ W1,
    const float* __restrict__ b1, const float* __restrict__ W2,
    const float* __restrict__ b2, float* __restrict__ out,
    const int* __restrict__ ws) {
  int bid = blockIdx.x;
  if (bid >= ws[256]) return;                 // uniform early-exit for unused blocks
  const int* item = ws + 272 + 3 * bid;
  int cat = item[0], start = item[1], cnt = item[2];
  const int* sorted = ws + 1024;

  // xh: x tile during layer1, h tile during layer2. Stride 132 (not 128):
  //   layer1 x-read banks (4t+d)%32 spread over 8 token-lanes -> conflict-free,
  //   and 132*4=528B keeps float4 row alignment.
  __shared__ float xh[TPB][132];
  __shared__ float w1t[32][128];              // 32-row d-tile of W1[cat]
  __shared__ int   toks[TPB];

  int tid = threadIdx.x;
  if (tid < TPB) toks[tid] = (tid < cnt) ? sorted[start + tid] : sorted[start];
  __syncthreads();

  // ---- stage x[cnt][128] into LDS (coalesced float4 per row) ----
  {
    int f4 = tid & 31;          // 32 float4 per 128-float row
    int r0 = tid >> 5;          // 8 row-groups
    #pragma unroll
    for (int it = 0; it < 8; ++it) {
      int i = r0 + (it << 3);
      if (i < cnt) {
        float4 v = ((const float4*)(x + (size_t)toks[i] * D_IN))[f4];
        *(float4*)&xh[i][f4 << 2] = v;
      }
    }
  }

  // ---- layer1: h[64][128] = x @ W1[cat]; per-thread tile 8 tokens x 4 cols ----
  int c0 = (tid >> 3) << 2;     // 32 col-groups * 4 cols = 128
  int tg = tid & 7;             // token stride 8
  float4 acc[8];
  #pragma unroll
  for (int j = 0; j < 8; ++j) acc[j] = make_float4(0.f, 0.f, 0.f, 0.f);

  for (int dt = 0; dt < 4; ++dt) {
    __syncthreads();
    {   // stage W1 rows [dt*32, dt*32+32): coalesced
      int f4 = tid & 31;
      int r0 = tid >> 5;
      #pragma unroll
      for (int rr = 0; rr < 4; ++rr) {
        int r = r0 + (rr << 3);
        float4 v = ((const float4*)(W1 + ((size_t)cat * D_IN + dt * 32 + r) * H_MID))[f4];
        *(float4*)&w1t[r][f4 << 2] = v;
      }
    }
    __syncthreads();
    #pragma unroll 4
    for (int d = 0; d < 32; ++d) {
      float4 w = *(float4*)&w1t[d][c0];
      #pragma unroll
      for (int j = 0; j < 8; ++j) {
        float xv = xh[tg + (j << 3)][(dt << 5) + d];   // rows >= cnt: garbage, discarded
        acc[j].x = fmaf(xv, w.x, acc[j].x);
        acc[j].y = fmaf(xv, w.y, acc[j].y);
        acc[j].z = fmaf(xv, w.z, acc[j].z);
        acc[j].w = fmaf(xv, w.w, acc[j].w);
      }
    }
  }

  // ---- bias + relu, write h back into xh ----
  float4 b1v = *(const float4*)(b1 + (size_t)cat * H_MID + c0);
  __syncthreads();
  #pragma unroll
  for (int j = 0; j < 8; ++j) {
    float4 hv;
    hv.x = fmaxf(acc[j].x + b1v.x, 0.f);
    hv.y = fmaxf(acc[j].y + b1v.y, 0.f);
    hv.z = fmaxf(acc[j].z + b1v.z, 0.f);
    hv.w = fmaxf(acc[j].w + b1v.w, 0.f);
    *(float4*)&xh[tg + (j << 3)][c0] = hv;
  }
  __syncthreads();

  // ---- layer2: out[64][64] = h @ W2[cat]; per-thread tile 4 tokens x 4 cols ----
  int o0  = (tid >> 4) << 2;    // 16 col-groups * 4 = 64
  int tg2 = tid & 15;           // token stride 16
  float4 acc2[4];
  #pragma unroll
  for (int j = 0; j < 4; ++j) acc2[j] = make_float4(0.f, 0.f, 0.f, 0.f);

  for (int h0 = 0; h0 < H_MID; h0 += 4) {
    float4 w2v[4];
    #pragma unroll
    for (int k = 0; k < 4; ++k)
      w2v[k] = *(const float4*)(W2 + ((size_t)cat * H_MID + h0 + k) * O_OUT + o0);
    #pragma unroll
    for (int k = 0; k < 4; ++k) {
      #pragma unroll
      for (int j = 0; j < 4; ++j) {
        float hv = xh[tg2 + (j << 4)][h0 + k];
        acc2[j].x = fmaf(hv, w2v[k].x, acc2[j].x);
        acc2[j].y = fmaf(hv, w2v[k].y, acc2[j].y);
        acc2[j].z = fmaf(hv, w2v[k].z, acc2[j].z);
        acc2[j].w = fmaf(hv, w2v[k].w, acc2[j].w);
      }
    }
  }

  float4 b2v = *(const float4*)(b2 + (size_t)cat * O_OUT + o0);
  #pragma unroll
  for (int j = 0; j < 4; ++j) {
    int t = tg2 + (j << 4);
    if (t < cnt) {
      float4 r;
      r.x = acc2[j].x + b2v.x;
      r.y = acc2[j].y + b2v.y;
      r.z = acc2[j].z + b2v.z;
      r.w = acc2[j].w + b2v.w;
      *(float4*)(out + (size_t)toks[t] * O_OUT + o0) = r;
    }
  }
}

extern "C" void kernel_launch(void* const* d_in, const int* in_sizes, int n_in,
                              void* d_out, int out_size, void* d_ws, size_t ws_size,
                              hipStream_t stream) {
  const float* x       = (const float*)d_in[0];
  const int*   cat_ids = (const int*)  d_in[1];
  const float* W1      = (const float*)d_in[2];
  const float* b1      = (const float*)d_in[3];
  const float* W2      = (const float*)d_in[4];
  const float* b2      = (const float*)d_in[5];
  float* out = (float*)d_out;
  int*   ws  = (int*)d_ws;

  zero_counts_kernel<<<1, 128, 0, stream>>>(ws);
  count_kernel<<<N_TOK / 256, 256, 0, stream>>>(cat_ids, ws);
  scan_build_kernel<<<1, 128, 0, stream>>>(ws);
  scatter_kernel<<<N_TOK / 256, 256, 0, stream>>>(cat_ids, ws);
  mlp_kernel<<<MAX_ITEMS, 256, 0, stream>>>(x, W1, b1, W2, b2, out, ws);
}

// Round 2
// 99.466 us; speedup vs baseline: 1.1936x; 1.1936x over previous
//
#include <hip/hip_runtime.h>

// CategorySpecificMLP: out = relu(x @ W1[cat] + b1[cat]) @ W2[cat] + b2[cat]
// N=8192, C=100, D=128, H=128, O=64, fp32.
//
// R2: (1) fused single-block prologue (count+scan+build+scatter via LDS
// atomics) -> 2 launches total; (2) TPB 64->32 => 356 blocks (1.4/CU) for
// latency hiding; (3) float4 LDS reads of x in layer1 (4x fewer LDS issue
// slots vs scalar).

#define N_TOK 8192
#define C_CAT 100
#define D_IN  128
#define H_MID 128
#define O_OUT 64
#define TPB   32                          // tokens per mlp block
#define MAX_ITEMS (C_CAT + N_TOK / TPB)   // 356: sum ceil(n_c/TPB) <= C + N/TPB

// ws layout (ints):
//   [256]              n_items
//   [272, 272+3*356)   work items (cat, start, cnt)
//   [2048, 2048+N)     token ids grouped by category

#define COMP(v,k) ((k)==0?(v).x:((k)==1?(v).y:((k)==2?(v).z:(v).w)))

__global__ __launch_bounds__(1024) void prologue_kernel(
    const int* __restrict__ cat_ids, int* __restrict__ ws) {
  __shared__ int cnt[C_CAT];
  __shared__ int cur[C_CAT];
  __shared__ int sc[128], sk[128];
  int t = threadIdx.x;
  if (t < C_CAT) cnt[t] = 0;
  __syncthreads();

  int ids[8];
  #pragma unroll
  for (int k = 0; k < 8; ++k) {
    ids[k] = cat_ids[t + (k << 10)];
    atomicAdd(&cnt[ids[k]], 1);
  }
  __syncthreads();

  int v = 0, ck = 0;
  if (t < 128) {
    v  = (t < C_CAT) ? cnt[t] : 0;
    ck = (v + TPB - 1) / TPB;
    sc[t] = v; sk[t] = ck;
  }
  __syncthreads();
  for (int off = 1; off < 128; off <<= 1) {
    int a = 0, b = 0;
    if (t < 128 && t >= off) { a = sc[t - off]; b = sk[t - off]; }
    __syncthreads();
    if (t < 128) { sc[t] += a; sk[t] += b; }
    __syncthreads();
  }
  if (t < C_CAT) {
    int start = sc[t] - v;     // exclusive prefix of counts
    int ibase = sk[t] - ck;    // exclusive prefix of chunk counts
    cur[t] = start;
    int* items = ws + 272;
    for (int k = 0; k < ck; ++k) {
      items[3 * (ibase + k) + 0] = t;
      items[3 * (ibase + k) + 1] = start + k * TPB;
      items[3 * (ibase + k) + 2] = min(TPB, v - k * TPB);
    }
  }
  if (t == 127) ws[256] = sk[127];
  __syncthreads();

  #pragma unroll
  for (int k = 0; k < 8; ++k) {
    int pos = atomicAdd(&cur[ids[k]], 1);
    ws[2048 + pos] = t + (k << 10);
  }
}

__global__ __launch_bounds__(256) void mlp_kernel(
    const float* __restrict__ x,  const float* __restrict__ W1,
    const float* __restrict__ b1, const float* __restrict__ W2,
    const float* __restrict__ b2, float* __restrict__ out,
    const int* __restrict__ ws) {
  int bid = blockIdx.x;
  if (bid >= ws[256]) return;
  const int* item = ws + 272 + 3 * bid;
  int cat = item[0], start = item[1], cnt = item[2];
  const int* sorted = ws + 2048;

  // stride 132: layer1 x float4 reads hit all 32 banks exactly once
  // (bank quad (4t+d0)%32, t=0..7); b32/h patterns <=2-way (free).
  __shared__ float xh[TPB][132];
  __shared__ float w1t[32][128];
  __shared__ int   toks[TPB];

  int tid = threadIdx.x;
  if (tid < TPB) toks[tid] = (tid < cnt) ? sorted[start + tid] : sorted[start];
  __syncthreads();

  // ---- stage x[cnt][128] (coalesced float4) ----
  {
    int f4 = tid & 31;
    int r0 = tid >> 5;
    #pragma unroll
    for (int it = 0; it < 4; ++it) {
      int i = r0 + (it << 3);
      if (i < cnt) {
        float4 vv = ((const float4*)(x + (size_t)toks[i] * D_IN))[f4];
        *(float4*)&xh[i][f4 << 2] = vv;
      }
    }
  }

  // ---- layer1: h[32][128]; per-thread 4 tokens x 4 cols ----
  int c0 = (tid >> 3) << 2;     // 32 col-groups * 4 = 128
  int tg = tid & 7;             // token stride 8
  float4 acc[4];
  #pragma unroll
  for (int j = 0; j < 4; ++j) acc[j] = make_float4(0.f, 0.f, 0.f, 0.f);

  for (int dt = 0; dt < 4; ++dt) {
    __syncthreads();
    {   // stage W1 rows [dt*32, dt*32+32)
      int f4 = tid & 31;
      int r0 = tid >> 5;
      #pragma unroll
      for (int rr = 0; rr < 4; ++rr) {
        int r = r0 + (rr << 3);
        float4 vv = ((const float4*)(W1 + ((size_t)cat * D_IN + dt * 32 + r) * H_MID))[f4];
        *(float4*)&w1t[r][f4 << 2] = vv;
      }
    }
    __syncthreads();
    #pragma unroll
    for (int dq = 0; dq < 8; ++dq) {
      float4 xv[4];
      #pragma unroll
      for (int j = 0; j < 4; ++j)
        xv[j] = *(float4*)&xh[tg + (j << 3)][(dt << 5) + (dq << 2)];
      #pragma unroll
      for (int k = 0; k < 4; ++k) {
        float4 wv = *(float4*)&w1t[(dq << 2) + k][c0];
        #pragma unroll
        for (int j = 0; j < 4; ++j) {
          float xs = COMP(xv[j], k);
          acc[j].x = fmaf(xs, wv.x, acc[j].x);
          acc[j].y = fmaf(xs, wv.y, acc[j].y);
          acc[j].z = fmaf(xs, wv.z, acc[j].z);
          acc[j].w = fmaf(xs, wv.w, acc[j].w);
        }
      }
    }
  }

  // ---- bias + relu, h back into xh ----
  float4 b1v = *(const float4*)(b1 + (size_t)cat * H_MID + c0);
  __syncthreads();
  #pragma unroll
  for (int j = 0; j < 4; ++j) {
    float4 hv;
    hv.x = fmaxf(acc[j].x + b1v.x, 0.f);
    hv.y = fmaxf(acc[j].y + b1v.y, 0.f);
    hv.z = fmaxf(acc[j].z + b1v.z, 0.f);
    hv.w = fmaxf(acc[j].w + b1v.w, 0.f);
    *(float4*)&xh[tg + (j << 3)][c0] = hv;
  }
  __syncthreads();

  // ---- layer2: out[32][64]; per-thread 2 tokens x 4 cols ----
  int o0  = (tid >> 4) << 2;    // 16 col-groups * 4 = 64
  int tg2 = tid & 15;           // token stride 16
  float4 acc2[2];
  acc2[0] = make_float4(0.f, 0.f, 0.f, 0.f);
  acc2[1] = make_float4(0.f, 0.f, 0.f, 0.f);

  #pragma unroll 4
  for (int hq = 0; hq < 32; ++hq) {
    float4 hv[2];
    hv[0] = *(float4*)&xh[tg2][hq << 2];
    hv[1] = *(float4*)&xh[tg2 + 16][hq << 2];
    #pragma unroll
    for (int k = 0; k < 4; ++k) {
      float4 wv = *(const float4*)(W2 + ((size_t)cat * H_MID + (hq << 2) + k) * O_OUT + o0);
      #pragma unroll
      for (int j = 0; j < 2; ++j) {
        float hs = COMP(hv[j], k);
        acc2[j].x = fmaf(hs, wv.x, acc2[j].x);
        acc2[j].y = fmaf(hs, wv.y, acc2[j].y);
        acc2[j].z = fmaf(hs, wv.z, acc2[j].z);
        acc2[j].w = fmaf(hs, wv.w, acc2[j].w);
      }
    }
  }

  float4 b2v = *(const float4*)(b2 + (size_t)cat * O_OUT + o0);
  #pragma unroll
  for (int j = 0; j < 2; ++j) {
    int tk = tg2 + (j << 4);
    if (tk < cnt) {
      float4 r;
      r.x = acc2[j].x + b2v.x;
      r.y = acc2[j].y + b2v.y;
      r.z = acc2[j].z + b2v.z;
      r.w = acc2[j].w + b2v.w;
      *(float4*)(out + (size_t)toks[tk] * O_OUT + o0) = r;
    }
  }
}

extern "C" void kernel_launch(void* const* d_in, const int* in_sizes, int n_in,
                              void* d_out, int out_size, void* d_ws, size_t ws_size,
                              hipStream_t stream) {
  const float* x       = (const float*)d_in[0];
  const int*   cat_ids = (const int*)  d_in[1];
  const float* W1      = (const float*)d_in[2];
  const float* b1      = (const float*)d_in[3];
  const float* W2      = (const float*)d_in[4];
  const float* b2      = (const float*)d_in[5];
  float* out = (float*)d_out;
  int*   ws  = (int*)d_ws;

  prologue_kernel<<<1, 1024, 0, stream>>>(cat_ids, ws);
  mlp_kernel<<<MAX_ITEMS, 256, 0, stream>>>(x, W1, b1, W2, b2, out, ws);
}